// Round 1
// baseline (11.349 us; speedup 1.0000x reference)
//
#include <hip/hip_runtime.h>

// PhysicsNet: only live outputs are
//   out[0] = kinetic  = sum_n 0.5 * mass[n] * |v_n|^2,  v_n = x[n, 3:6, 1]
//   out[1] = internal = E * ebeta[0]   (LayerNorm over size-1 axis => exactly ebeta)
//
// x layout (N, 6, 2) row-major: node n occupies floats [12n, 12n+12).
// v components at 12n+7, 12n+9, 12n+11. Loaded via two aligned float4s.

#define BLK 256
#define NBLOCKS 256

__global__ __launch_bounds__(BLK) void kinetic_partial(
    const float* __restrict__ x, const float* __restrict__ mass,
    float* __restrict__ partials, int N) {
  __shared__ float red[BLK / 64];
  int tid = threadIdx.x;
  int gid = blockIdx.x * BLK + tid;
  int stride = gridDim.x * BLK;
  float acc = 0.f;
  for (int n = gid; n < N; n += stride) {
    const float4* f4 = reinterpret_cast<const float4*>(x + (size_t)n * 12);
    float4 a = f4[1];  // floats 12n+4 .. 12n+7 : a.w = vx
    float4 b = f4[2];  // floats 12n+8 .. 12n+11: b.y = vy, b.w = vz
    float vx = a.w, vy = b.y, vz = b.w;
    acc += 0.5f * mass[n] * (vx * vx + vy * vy + vz * vz);
  }
  // wave64 butterfly reduce
  #pragma unroll
  for (int off = 32; off > 0; off >>= 1) acc += __shfl_down(acc, off, 64);
  if ((tid & 63) == 0) red[tid >> 6] = acc;
  __syncthreads();
  if (tid == 0) {
    float s = 0.f;
    #pragma unroll
    for (int w = 0; w < BLK / 64; ++w) s += red[w];
    partials[blockIdx.x] = s;
  }
}

__global__ __launch_bounds__(BLK) void finalize(
    const float* __restrict__ partials, int nb,
    const float* __restrict__ ebeta, int E, float* __restrict__ out) {
  __shared__ float red[BLK / 64];
  int tid = threadIdx.x;
  float acc = 0.f;
  for (int i = tid; i < nb; i += BLK) acc += partials[i];
  #pragma unroll
  for (int off = 32; off > 0; off >>= 1) acc += __shfl_down(acc, off, 64);
  if ((tid & 63) == 0) red[tid >> 6] = acc;
  __syncthreads();
  if (tid == 0) {
    float s = 0.f;
    #pragma unroll
    for (int w = 0; w < BLK / 64; ++w) s += red[w];
    out[0] = s;                       // kinetic
    out[1] = ebeta[0] * (float)E;     // internal (== 0 for given inputs)
  }
}

extern "C" void kernel_launch(void* const* d_in, const int* in_sizes, int n_in,
                              void* d_out, int out_size, void* d_ws, size_t ws_size,
                              hipStream_t stream) {
  const float* x     = (const float*)d_in[0];
  const float* mass  = (const float*)d_in[1];
  const float* ebeta = (const float*)d_in[15];
  int N = in_sizes[1];   // node_mass has N elements
  int E = in_sizes[2];   // element_materials has E elements

  float* partials = (float*)d_ws;
  kinetic_partial<<<NBLOCKS, BLK, 0, stream>>>(x, mass, partials, N);
  finalize<<<1, BLK, 0, stream>>>(partials, NBLOCKS, ebeta, E, (float*)d_out);
}